// Round 18
// baseline (1458.580 us; speedup 1.0000x reference)
//
#include <hip/hip_runtime.h>
#include <stddef.h>
#include <stdint.h>

// Elman RNN: out[t,b,u] = h_t = tanh(x_t @ Wx + h_{t-1} @ Wh + bias)
// B=128, T=512, D=128, U=512. Output [T, B, U] float32.
//
// pgemm (f16 dot2): P = x@Wx + bias -> d_out. (~15 us, validated)
// rnn r18 (4-wave): one WG (256 thr, 4 waves = 1/SIMD) per batch row.
//   Wave w owns cols [128w, 128w+128) = 8 col-tiles. 128 MFMAs/wave/step.
//   DS-throughput theory: r13's 8-wave config issues 256 ds_read_b128/CU/step
//   (~3072 cy on the shared LDS unit) > MFMA floor 2480 cy -> DS-bound.
//   4 waves halve the duplicated A-broadcast reads (128->64/CU) and the
//   1-wave/SIMD VGPR budget (~450, m08 no-spill line) lets each wave hold
//   89/128 W-frags in registers: DS -> 4x(39+16)=220 reads ~ 2640 cy.
//   W frags: slabs 0..10 all 8 ct + slab 11 ct0 in regs (356 VGPRs, pinned
//   per r13); slab 11 ct1..7 + slabs 12..15 in LDS (156 KB).
//   Schedule: r13's proven group-lookahead (one 8-frag stage); r17's
//   lgkm-only barrier.
//   Layouts (validated r10/r13, absmax 0.0039):
//     A[i][k]: lane = i + 16*(k/8), elem = k%8   (row 0 broadcast to all i)
//     B[k][j]: lane = j + 16*(k/8), elem = k%8
//     D[i][j]: lane = j + 16*(i/4), reg = i%4    (row 0 -> lanes 0-15, .x)

constexpr int B = 128;
constexpr int T = 512;
constexpr int D = 128;
constexpr int U = 512;

typedef _Float16 f16;
typedef _Float16 f16x2 __attribute__((ext_vector_type(2)));
typedef _Float16 f16x8 __attribute__((ext_vector_type(8)));
typedef __fp16   fp16x2 __attribute__((ext_vector_type(2)));
typedef float    f32x4 __attribute__((ext_vector_type(4)));
typedef unsigned int u32;

union U32H2 { u32 u; f16x2 h; fp16x2 p; };

static __device__ __forceinline__ u32 pk(float a, float b) {
    U32H2 c; c.p = __builtin_amdgcn_cvt_pkrtz(a, b); return c.u;
}

#if __has_builtin(__builtin_amdgcn_fdot2)
static __device__ __forceinline__ float fdot2(u32 a, u32 b, float c) {
    U32H2 x, y; x.u = a; y.u = b;
    return __builtin_amdgcn_fdot2(x.h, y.h, c, false);
}
#else
static __device__ __forceinline__ float fdot2(u32 a, u32 b, float c) {
    U32H2 x, y; x.u = a; y.u = b;
    return c + (float)x.h.x * (float)y.h.x + (float)x.h.y * (float)y.h.y;
}
#endif

static __device__ __forceinline__ float fast_tanh(float x) {
    float e = __expf(2.0f * x);
    return 1.0f - 2.0f * __builtin_amdgcn_rcpf(e + 1.0f);
}

// ---------------------------------------------------------------------------
// Kernel 1: P = x @ Wx + bias  (M=T*B, K=D=128 one-shot, N=U) — f16 dot2
// ---------------------------------------------------------------------------
__global__ __launch_bounds__(256) void pgemm_kernel(
    const float* __restrict__ x,     // [B, T, D]
    const float* __restrict__ Wx,    // [D, U]
    const float* __restrict__ bias,  // [U]
    float* __restrict__ P)           // [T*B, U]  (== d_out)
{
    __shared__ u32 xs[128][66];      // [row][k-pair]   (+2 pad)
    __shared__ u32 ws[64][132];      // [k-pair][col]   (+4 pad)

    const int rb  = blockIdx.x;
    const int cb  = blockIdx.y;
    const int tid = threadIdx.x;
    const int tr  = tid >> 4;
    const int tcc = tid & 15;

    const float4* x4 = (const float4*)x;
#pragma unroll
    for (int l = 0; l < 16; ++l) {
        int idx = tid + l * 256;
        int r   = idx >> 5;
        int q   = idx & 31;
        int m   = rb * 128 + r;
        int b_  = m & 127;
        int t_  = m >> 7;
        float4 v = x4[((size_t)b_ * T + t_) * 32 + q];
        xs[r][2 * q]     = pk(v.x, v.y);
        xs[r][2 * q + 1] = pk(v.z, v.w);
    }
    const float4* W4 = (const float4*)Wx;
#pragma unroll
    for (int l = 0; l < 8; ++l) {
        int idx = tid + l * 256;
        int kp  = idx >> 5;
        int q   = idx & 31;
        float4 a = W4[(size_t)(2 * kp)     * 128 + cb * 32 + q];
        float4 c = W4[(size_t)(2 * kp + 1) * 128 + cb * 32 + q];
        uint4 w;
        w.x = pk(a.x, c.x); w.y = pk(a.y, c.y);
        w.z = pk(a.z, c.z); w.w = pk(a.w, c.w);
        *(uint4*)&ws[kp][4 * q] = w;
    }
    __syncthreads();

    float acc[8][8];
#pragma unroll
    for (int i = 0; i < 8; ++i)
#pragma unroll
        for (int j = 0; j < 8; ++j) acc[i][j] = 0.f;

#pragma unroll 2
    for (int kp = 0; kp < 64; ++kp) {
        u32 xv[8], wv[8];
#pragma unroll
        for (int i = 0; i < 8; ++i) xv[i] = xs[tr + 16 * i][kp];
#pragma unroll
        for (int j = 0; j < 8; ++j) wv[j] = ws[kp][tcc + 16 * j];
#pragma unroll
        for (int i = 0; i < 8; ++i)
#pragma unroll
            for (int j = 0; j < 8; ++j)
                acc[i][j] = fdot2(xv[i], wv[j], acc[i][j]);
    }

#pragma unroll
    for (int j = 0; j < 8; ++j) {
        int c    = cb * 128 + tcc + 16 * j;
        float bv = bias[c];
#pragma unroll
        for (int i = 0; i < 8; ++i) {
            int m = rb * 128 + tr + 16 * i;
            P[(size_t)m * U + c] = acc[i][j] + bv;
        }
    }
}

// ---------------------------------------------------------------------------
// Kernel 2: recurrence via MFMA, one WG (256 thr, 4 waves) per batch row.
// ---------------------------------------------------------------------------
__global__ __launch_bounds__(256, 1) void rnn_kernel(
    const float* __restrict__ Wh,    // [U, U] f32
    float* __restrict__ out)         // [T*B, U]; P on entry, h on exit
{
    // WL: 4 waves x 39 frag slots x 1024 B = 156 KB
    __shared__ __align__(16) u32 WL[39936];
    __shared__ __align__(16) u32 hbuf[2][256];   // h f16 [2 parity][512]

    const int tid = threadIdx.x;
    const int w   = tid >> 6;        // wave 0..3 (owns cols 128w..128w+127)
    const int l   = tid & 63;        // lane
    const int lg  = l >> 4;          // k-octet group 0..3
    const int lc  = l & 15;          // col-in-tile
    const int b   = blockIdx.x;
    const int cb  = 128 * w;

    // ---- init: register B-fragments: slabs 0..10 (all ct) + slab 11 ct0 ----
    // frag(ct, s) elem e = Wh[32s + 8*lg + e][cb + 16ct + lc]
    f16x8 Wf[8][11];
    f16x8 Wf11;
#pragma unroll
    for (int ct = 0; ct < 8; ++ct) {
#pragma unroll
        for (int s = 0; s < 11; ++s) {
            const float* src = Wh + (size_t)(32 * s + 8 * lg) * U
                             + cb + 16 * ct + lc;
            f16x8 f;
#pragma unroll
            for (int e = 0; e < 8; ++e) f[e] = (f16)src[(size_t)e * U];
            Wf[ct][s] = f;
        }
    }
    {
        const float* src = Wh + (size_t)(32 * 11 + 8 * lg) * U + cb + lc;
        f16x8 f;
#pragma unroll
        for (int e = 0; e < 8; ++e) f[e] = (f16)src[(size_t)e * U];
        Wf11 = f;
    }
    // PIN (r13 lesson): opaque defs -> no remat-from-global in the t-loop.
#pragma unroll
    for (int ct = 0; ct < 8; ++ct)
#pragma unroll
        for (int s = 0; s < 11; ++s)
            asm("" : "+v"(Wf[ct][s]));
    asm("" : "+v"(Wf11));

    // ---- init: LDS frags. idx = (s-11)*8 + ct - 1 for (11,1..7),(12..15,0..7)
#pragma unroll
    for (int s = 11; s < 16; ++s) {
#pragma unroll
        for (int ct = 0; ct < 8; ++ct) {
            if (s == 11 && ct == 0) continue;
            int idx = (s - 11) * 8 + ct - 1;    // 0..38
            const float* src = Wh + (size_t)(32 * s + 8 * lg) * U
                             + cb + 16 * ct + lc;
            f16x8 f;
#pragma unroll
            for (int e = 0; e < 8; ++e) f[e] = (f16)src[(size_t)e * U];
            *(f16x8*)&WL[((w * 39 + idx) * 64 + l) * 4] = f;
        }
    }

    if (tid < 256) { hbuf[0][tid] = 0u; hbuf[1][tid] = 0u; }
    __syncthreads();

    float* outb = out + (size_t)b * U;

    // P prefetch for t=0 (lanes 0-15 own cols cb+16ct+lc)
    float pv[8];
#pragma unroll
    for (int ct = 0; ct < 8; ++ct) pv[ct] = 0.f;
    if (l < 16) {
#pragma unroll
        for (int ct = 0; ct < 8; ++ct) pv[ct] = outb[cb + 16 * ct + lc];
    }

    for (int t = 0; t < T; ++t) {
        const int par = t & 1;
        const f16* hb = (const f16*)hbuf[par];

        f32x4 acc[8];
#pragma unroll
        for (int ct = 0; ct < 8; ++ct) acc[ct] = (f32x4)0.f;

#define ALOAD(s) (*(const f16x8*)&hb[32 * (s) + 8 * lg])
#define WLREAD(j) (*(const f16x8*)&WL[((w * 39 + (j)) * 64 + l) * 4])
#define MM(ct, a, bb) acc[ct] = __builtin_amdgcn_mfma_f32_16x16x32_f16((a), (bb), acc[ct], 0, 0, 0)
#define REGSLAB(s)                                                        \
        {                                                                 \
            f16x8 a_ = ALOAD(s);                                          \
            MM(0, a_, Wf[0][s]); MM(1, a_, Wf[1][s]);                     \
            MM(2, a_, Wf[2][s]); MM(3, a_, Wf[3][s]);                     \
            MM(4, a_, Wf[4][s]); MM(5, a_, Wf[5][s]);                     \
            MM(6, a_, Wf[6][s]); MM(7, a_, Wf[7][s]);                     \
        }

        f16x8 sg0, sg1, sg2, sg3, sg4, sg5, sg6, sg7;

        // G11 (7 frags: slab 11 ct1..7)
        sg0 = WLREAD(0); sg1 = WLREAD(1); sg2 = WLREAD(2); sg3 = WLREAD(3);
        sg4 = WLREAD(4); sg5 = WLREAD(5); sg6 = WLREAD(6);
        REGSLAB(0) REGSLAB(1)
        {   // consume slab 11
            f16x8 a_ = ALOAD(11);
            MM(0, a_, Wf11);
            MM(1, a_, sg0); MM(2, a_, sg1); MM(3, a_, sg2); MM(4, a_, sg3);
            MM(5, a_, sg4); MM(6, a_, sg5); MM(7, a_, sg6);
        }
        // G12 (idx 7..14)
        sg0 = WLREAD(7);  sg1 = WLREAD(8);  sg2 = WLREAD(9);  sg3 = WLREAD(10);
        sg4 = WLREAD(11); sg5 = WLREAD(12); sg6 = WLREAD(13); sg7 = WLREAD(14);
        REGSLAB(2) REGSLAB(3)
        {
            f16x8 a_ = ALOAD(12);
            MM(0, a_, sg0); MM(1, a_, sg1); MM(2, a_, sg2); MM(3, a_, sg3);
            MM(4, a_, sg4); MM(5, a_, sg5); MM(6, a_, sg6); MM(7, a_, sg7);
        }
        // G13 (idx 15..22)
        sg0 = WLREAD(15); sg1 = WLREAD(16); sg2 = WLREAD(17); sg3 = WLREAD(18);
        sg4 = WLREAD(19); sg5 = WLREAD(20); sg6 = WLREAD(21); sg7 = WLREAD(22);
        REGSLAB(4) REGSLAB(5)
        {
            f16x8 a_ = ALOAD(13);
            MM(0, a_, sg0); MM(1, a_, sg1); MM(2, a_, sg2); MM(3, a_, sg3);
            MM(4, a_, sg4); MM(5, a_, sg5); MM(6, a_, sg6); MM(7, a_, sg7);
        }
        // G14 (idx 23..30)
        sg0 = WLREAD(23); sg1 = WLREAD(24); sg2 = WLREAD(25); sg3 = WLREAD(26);
        sg4 = WLREAD(27); sg5 = WLREAD(28); sg6 = WLREAD(29); sg7 = WLREAD(30);
        REGSLAB(6) REGSLAB(7)
        {
            f16x8 a_ = ALOAD(14);
            MM(0, a_, sg0); MM(1, a_, sg1); MM(2, a_, sg2); MM(3, a_, sg3);
            MM(4, a_, sg4); MM(5, a_, sg5); MM(6, a_, sg6); MM(7, a_, sg7);
        }
        // G15 (idx 31..38)
        sg0 = WLREAD(31); sg1 = WLREAD(32); sg2 = WLREAD(33); sg3 = WLREAD(34);
        sg4 = WLREAD(35); sg5 = WLREAD(36); sg6 = WLREAD(37); sg7 = WLREAD(38);
        REGSLAB(8) REGSLAB(9) REGSLAB(10)
        {
            f16x8 a_ = ALOAD(15);
            MM(0, a_, sg0); MM(1, a_, sg1); MM(2, a_, sg2); MM(3, a_, sg3);
            MM(4, a_, sg4); MM(5, a_, sg5); MM(6, a_, sg6); MM(7, a_, sg7);
        }
#undef REGSLAB
#undef MM
#undef WLREAD
#undef ALOAD

        // tail (r13 order): row 0 of D lives in lanes 0-15, reg [0]
        float nv[8];
#pragma unroll
        for (int ct = 0; ct < 8; ++ct) nv[ct] = 0.f;
        if (l < 16) {
            float* prow = outb + (size_t)t * (B * U);
            const float* prown = outb + (size_t)((t + 1 < T) ? t + 1 : t) * (B * U);
            f16* hbn = (f16*)hbuf[par ^ 1];
#pragma unroll
            for (int ct = 0; ct < 8; ++ct) {
                float h = fast_tanh(pv[ct] + acc[ct][0]);
                prow[cb + 16 * ct + lc] = h;
                hbn[cb + 16 * ct + lc] = (f16)h;
                nv[ct] = prown[cb + 16 * ct + lc];
            }
        }

        // r17 barrier: LDS-only visibility; global loads/stores stay in
        // flight and complete under the next step's MFMA phase.
        asm volatile("s_waitcnt lgkmcnt(0)" ::: "memory");
        __builtin_amdgcn_s_barrier();
        __builtin_amdgcn_sched_barrier(0);

#pragma unroll
        for (int ct = 0; ct < 8; ++ct) pv[ct] = nv[ct];
    }
}

// ---------------------------------------------------------------------------
extern "C" void kernel_launch(void* const* d_in, const int* in_sizes, int n_in,
                              void* d_out, int out_size, void* d_ws, size_t ws_size,
                              hipStream_t stream)
{
    (void)d_ws; (void)ws_size; (void)in_sizes; (void)n_in; (void)out_size;
    const float* x    = (const float*)d_in[0];  // [B, T, D]
    const float* Wx   = (const float*)d_in[1];  // [D, U]
    const float* Wh   = (const float*)d_in[2];  // [U, U]
    const float* bias = (const float*)d_in[3];  // [U]
    float* out = (float*)d_out;                 // [T, B, U]

    pgemm_kernel<<<dim3((T * B) / 128, U / 128), 256, 0, stream>>>(x, Wx, bias, out);
    rnn_kernel<<<B, 256, 0, stream>>>(Wh, out);
}